// Round 1
// baseline (13832.545 us; speedup 1.0000x reference)
//
#include <hip/hip_runtime.h>
#include <hip/hip_bf16.h>
#include <math.h>

#define NNODES 500000
#define BN_EPS 1e-5f

// ---------- atomics: force native HW fp atomics (agent scope, relaxed) ----------
__device__ __forceinline__ void atomAddF(float* p, float v) {
    __hip_atomic_fetch_add(p, v, __ATOMIC_RELAXED, __HIP_MEMORY_SCOPE_AGENT);
}
__device__ __forceinline__ void atomAddD(double* p, double v) {
    __hip_atomic_fetch_add(p, v, __ATOMIC_RELAXED, __HIP_MEMORY_SCOPE_AGENT);
}

// ---------- block-level reduce of CNT doubles, then atomic to dst[0..CNT) ----------
template<int CNT>
__device__ __forceinline__ void blk_reduce_atomic(double (&vals)[CNT], double* dst) {
    __shared__ double sh[CNT][4];
    int lane = threadIdx.x & 63, wid = threadIdx.x >> 6;
#pragma unroll
    for (int k = 0; k < CNT; ++k) {
        double v = vals[k];
#pragma unroll
        for (int o = 32; o; o >>= 1) v += __shfl_down(v, o);
        if (lane == 0) sh[k][wid] = v;
    }
    __syncthreads();
    if ((int)threadIdx.x < CNT) {
        double v = sh[threadIdx.x][0] + sh[threadIdx.x][1] + sh[threadIdx.x][2] + sh[threadIdx.x][3];
        atomAddD(dst + threadIdx.x, v);
    }
}

// ---------- tiny: h_row, a0/a1/a2 from weights only ----------
__global__ void k_t0(const float* __restrict__ Wi, const float* __restrict__ bi,
                     const float* __restrict__ Wg, const float* __restrict__ bg,
                     const float* __restrict__ Wt1, float* __restrict__ fs) {
    if (threadIdx.x || blockIdx.x) return;
    float xr[4];
    for (int j = 0; j < 4; ++j) {
        float s = bi[j];
        for (int k = 0; k < 12; ++k) s += Wi[k * 4 + j];
        xr[j] = s;
    }
    float hr[7];
    for (int j = 0; j < 7; ++j) {
        float s = bg[j];
        for (int k = 0; k < 4; ++k) s += xr[k] * Wg[k * 7 + j];
        hr[j] = 1.f / (1.f + expf(-s));
        fs[j] = hr[j];
    }
    for (int j = 0; j < 7; ++j) {
        float s0 = 0.f, s1 = 0.f, s2 = 0.f;
        for (int k = 0; k < 7; ++k) {
            s0 += hr[k] * Wt1[k * 7 + j];
            s1 += hr[k] * Wt1[(7 + k) * 7 + j];
            s2 += hr[k] * Wt1[(14 + k) * 7 + j];
        }
        fs[7 + j] = s0; fs[14 + j] = s1; fs[21 + j] = s2;
    }
}

// ---------- edge pass: degree ----------
__global__ void __launch_bounds__(256) k_deg(const int* __restrict__ dst, float* __restrict__ deg, int E) {
    int i = (blockIdx.x * blockDim.x + threadIdx.x) * 4;
    if (i + 3 < E) {
        int4 d = *reinterpret_cast<const int4*>(dst + i);
        atomAddF(deg + d.x, 1.f); atomAddF(deg + d.y, 1.f);
        atomAddF(deg + d.z, 1.f); atomAddF(deg + d.w, 1.f);
    } else {
        for (; i < E; ++i) atomAddF(deg + dst[i], 1.f);
    }
}

// ---------- node: deg -> norm ----------
__global__ void __launch_bounds__(256) k_norm(float* nrm, int n) {
    int i = blockIdx.x * blockDim.x + threadIdx.x;
    if (i < n) nrm[i] = 1.f / sqrtf(fmaxf(nrm[i], 1.f));
}

// ---------- edge pass: acc[dst] += val[src] (scalar) ----------
__global__ void __launch_bounds__(256) k_gs(const int* __restrict__ src, const int* __restrict__ dst,
                                            const float* __restrict__ val, float* __restrict__ acc, int E) {
    int i = (blockIdx.x * blockDim.x + threadIdx.x) * 4;
    if (i + 3 < E) {
        int4 s = *reinterpret_cast<const int4*>(src + i);
        int4 d = *reinterpret_cast<const int4*>(dst + i);
        atomAddF(acc + d.x, val[s.x]); atomAddF(acc + d.y, val[s.y]);
        atomAddF(acc + d.z, val[s.z]); atomAddF(acc + d.w, val[s.w]);
    } else {
        for (; i < E; ++i) atomAddF(acc + dst[i], val[src[i]]);
    }
}

// ---------- node: s1 finalize (s1 *= norm; s1n = s1*norm) ----------
__global__ void __launch_bounds__(256) k_s1fin(float* s1, float* s1n, const float* nrm, int n) {
    int i = blockIdx.x * blockDim.x + threadIdx.x;
    if (i < n) { float v = s1[i] * nrm[i]; s1[i] = v; s1n[i] = v * nrm[i]; }
}

// ---------- node: s2 finalize + moments of (s1,s2) ----------
__global__ void __launch_bounds__(256) k_s2fin_mom(float* s2, const float* s1, const float* nrm,
                                                   double* ds, int n) {
    double acc[5] = {0, 0, 0, 0, 0};
    for (int i = blockIdx.x * blockDim.x + threadIdx.x; i < n; i += gridDim.x * blockDim.x) {
        float v2 = s2[i] * nrm[i]; s2[i] = v2;
        float v1 = s1[i];
        acc[0] += v1; acc[1] += v2;
        acc[2] += (double)v1 * (double)v1;
        acc[3] += (double)v2 * (double)v2;
        acc[4] += (double)v1 * (double)v2;
    }
    blk_reduce_atomic<5>(acc, ds);
}

// ---------- tiny: BN1 folded coefficients d0,d1,d2 ----------
__global__ void k_t1(const double* __restrict__ ds, const float* __restrict__ fs,
                     const float* __restrict__ g1, const float* __restrict__ b1, float* __restrict__ fsg) {
    if (threadIdx.x || blockIdx.x) return;
    const double inv_n = 1.0 / (double)NNODES;
    float mu1 = (float)(ds[0] * inv_n), mu2 = (float)(ds[1] * inv_n);
    float V11 = (float)(ds[2] * inv_n) - mu1 * mu1;
    float V22 = (float)(ds[3] * inv_n) - mu2 * mu2;
    float V12 = (float)(ds[4] * inv_n) - mu1 * mu2;
    for (int j = 0; j < 7; ++j) {
        float a0 = fs[7 + j], a1 = fs[14 + j], a2 = fs[21 + j];
        float var = a1 * a1 * V11 + a2 * a2 * V22 + 2.f * a1 * a2 * V12;
        float ig = (1.f / sqrtf(var + BN_EPS)) * g1[j];
        fsg[j]      = b1[j] - (mu1 * a1 + mu2 * a2) * ig;  // d0
        fsg[7 + j]  = a1 * ig;                              // d1
        fsg[14 + j] = a2 * ig;                              // d2
    }
}

// ---------- node: h1n = relu(d0 + s1*d1 + s2*d2) * norm, stride-8 padded ----------
__global__ void __launch_bounds__(256) k_h1n(const float* __restrict__ s1, const float* __restrict__ s2,
                                             const float* __restrict__ nrm, const float* __restrict__ fsg,
                                             float* __restrict__ h1n, int n) {
    int i = blockIdx.x * blockDim.x + threadIdx.x;
    if (i >= n) return;
    float S1 = s1[i], S2 = s2[i], Nn = nrm[i];
    float o[8];
#pragma unroll
    for (int j = 0; j < 7; ++j)
        o[j] = fmaxf(fsg[j] + S1 * fsg[7 + j] + S2 * fsg[14 + j], 0.f) * Nn;
    o[7] = 0.f;
    float4* q = reinterpret_cast<float4*>(h1n + (size_t)i * 8);
    q[0] = make_float4(o[0], o[1], o[2], o[3]);
    q[1] = make_float4(o[4], o[5], o[6], o[7]);
}

// ---------- edge pass: 7-wide acc[dst] += xs[src] ----------
__global__ void __launch_bounds__(256) k_prop7(const int* __restrict__ src, const int* __restrict__ dst,
                                               const float* __restrict__ xs, float* __restrict__ acc, int E) {
    int i = (blockIdx.x * blockDim.x + threadIdx.x) * 4;
    if (i + 3 < E) {
        int4 s = *reinterpret_cast<const int4*>(src + i);
        int4 d = *reinterpret_cast<const int4*>(dst + i);
        int se[4] = {s.x, s.y, s.z, s.w};
        int de[4] = {d.x, d.y, d.z, d.w};
#pragma unroll
        for (int e = 0; e < 4; ++e) {
            const float4* p = reinterpret_cast<const float4*>(xs + (size_t)se[e] * 8);
            float4 a = p[0], b = p[1];
            float* q = acc + (size_t)de[e] * 8;
            atomAddF(q + 0, a.x); atomAddF(q + 1, a.y); atomAddF(q + 2, a.z); atomAddF(q + 3, a.w);
            atomAddF(q + 4, b.x); atomAddF(q + 5, b.y); atomAddF(q + 6, b.z);
        }
    } else {
        for (; i < E; ++i) {
            const float* p = xs + (size_t)src[i] * 8;
            float* q = acc + (size_t)dst[i] * 8;
            for (int j = 0; j < 7; ++j) atomAddF(q + j, p[j]);
        }
    }
}

// ---------- node: f1p = norm*acc (in place), bufB = f1p*norm ----------
__global__ void __launch_bounds__(256) k_scaleA(const float* __restrict__ nrm, float* __restrict__ bufA,
                                                float* __restrict__ bufB, int n) {
    int i = blockIdx.x * blockDim.x + threadIdx.x;
    if (i >= n) return;
    float Nn = nrm[i];
    float4* pa = reinterpret_cast<float4*>(bufA + (size_t)i * 8);
    float4 a = pa[0], b = pa[1];
    a.x *= Nn; a.y *= Nn; a.z *= Nn; a.w *= Nn;
    b.x *= Nn; b.y *= Nn; b.z *= Nn; b.w *= Nn;
    pa[0] = a; pa[1] = b;
    float4 c = a, d = b;
    c.x *= Nn; c.y *= Nn; c.z *= Nn; c.w *= Nn;
    d.x *= Nn; d.y *= Nn; d.z *= Nn; d.w *= Nn;
    float4* pb = reinterpret_cast<float4*>(bufB + (size_t)i * 8);
    pb[0] = c; pb[1] = d;
}

// ---------- node: x2 = [h1|f1p|f2p]@Wt2, store + column moments ----------
__global__ void __launch_bounds__(256) k_x2(const float* __restrict__ s1, const float* __restrict__ s2,
                                            const float* __restrict__ nrm, const float* __restrict__ fsg,
                                            const float* __restrict__ bufA, const float* __restrict__ bufC,
                                            const float* __restrict__ Wt2, float* __restrict__ x2o,
                                            double* __restrict__ ds, int n) {
    __shared__ float w[147];
    for (int k = threadIdx.x; k < 147; k += blockDim.x) w[k] = Wt2[k];
    float dc[21];
#pragma unroll
    for (int j = 0; j < 21; ++j) dc[j] = fsg[j];
    __syncthreads();
    double sx[7] = {0, 0, 0, 0, 0, 0, 0}, sq[7] = {0, 0, 0, 0, 0, 0, 0};
    for (int i = blockIdx.x * blockDim.x + threadIdx.x; i < n; i += gridDim.x * blockDim.x) {
        float S1 = s1[i], S2 = s2[i], Nn = nrm[i];
        float h1[7];
#pragma unroll
        for (int k = 0; k < 7; ++k) h1[k] = fmaxf(dc[k] + S1 * dc[7 + k] + S2 * dc[14 + k], 0.f);
        const float4* pa = reinterpret_cast<const float4*>(bufA + (size_t)i * 8);
        float4 fa = pa[0], fb = pa[1];
        const float4* pc = reinterpret_cast<const float4*>(bufC + (size_t)i * 8);
        float4 ca = pc[0], cb = pc[1];
        float f1p[7] = {fa.x, fa.y, fa.z, fa.w, fb.x, fb.y, fb.z};
        float f2p[7] = {ca.x * Nn, ca.y * Nn, ca.z * Nn, ca.w * Nn, cb.x * Nn, cb.y * Nn, cb.z * Nn};
        float x2[8];
#pragma unroll
        for (int j = 0; j < 7; ++j) {
            float s = 0.f;
#pragma unroll
            for (int k = 0; k < 7; ++k)
                s += h1[k] * w[k * 7 + j] + f1p[k] * w[(7 + k) * 7 + j] + f2p[k] * w[(14 + k) * 7 + j];
            x2[j] = s;
            sx[j] += s; sq[j] += (double)s * (double)s;
        }
        x2[7] = 0.f;
        float4* q = reinterpret_cast<float4*>(x2o + (size_t)i * 8);
        q[0] = make_float4(x2[0], x2[1], x2[2], x2[3]);
        q[1] = make_float4(x2[4], x2[5], x2[6], x2[7]);
    }
    double acc[14];
#pragma unroll
    for (int j = 0; j < 7; ++j) { acc[j] = sx[j]; acc[7 + j] = sq[j]; }
    blk_reduce_atomic<14>(acc, ds + 5);
}

// ---------- tiny: BN2 folded coefficients c0,c1 ----------
__global__ void k_t2(const double* __restrict__ ds, const float* __restrict__ g2,
                     const float* __restrict__ b2, float* __restrict__ fsg) {
    if (threadIdx.x || blockIdx.x) return;
    const double inv_n = 1.0 / (double)NNODES;
    for (int j = 0; j < 7; ++j) {
        float m = (float)(ds[5 + j] * inv_n);
        float v = (float)(ds[12 + j] * inv_n) - m * m;
        float ig = (1.f / sqrtf(v + BN_EPS)) * g2[j];
        fsg[21 + j] = b2[j] - m * ig;  // c0
        fsg[28 + j] = ig;              // c1
    }
}

// ---------- node: h2 column sums ----------
__global__ void __launch_bounds__(256) k_h2sum(const float* __restrict__ x2o, const float* __restrict__ fsg,
                                               double* __restrict__ ds, int n) {
    float c0[7], c1[7];
#pragma unroll
    for (int j = 0; j < 7; ++j) { c0[j] = fsg[21 + j]; c1[j] = fsg[28 + j]; }
    double acc[7] = {0, 0, 0, 0, 0, 0, 0};
    for (int i = blockIdx.x * blockDim.x + threadIdx.x; i < n; i += gridDim.x * blockDim.x) {
        const float4* p = reinterpret_cast<const float4*>(x2o + (size_t)i * 8);
        float4 a = p[0], b = p[1];
        float x[7] = {a.x, a.y, a.z, a.w, b.x, b.y, b.z};
#pragma unroll
        for (int j = 0; j < 7; ++j) acc[j] += (double)fmaxf(x[j] * c1[j] + c0[j], 0.f);
    }
    blk_reduce_atomic<7>(acc, ds + 19);
}

// ---------- tiny: embeddings + similarity MLP + sigmoid ----------
__global__ void k_final(const double* __restrict__ ds, const float* __restrict__ Wd, const float* __restrict__ bd,
                        const float* __restrict__ Ws0, const float* __restrict__ bs0,
                        const float* __restrict__ Ws1, const float* __restrict__ bs1,
                        const float* __restrict__ Ws2, const float* __restrict__ bs2,
                        const float* __restrict__ Ws3, const float* __restrict__ bs3,
                        const float* __restrict__ Wsim, const float* __restrict__ bsim,
                        float* __restrict__ out) {
    if (threadIdx.x || blockIdx.x) return;
    const double inv_n = 1.0 / (double)NNODES;
    float v[22];
    for (int g = 0; g < 2; ++g) {
        float hm[7];
        for (int j = 0; j < 7; ++j) hm[j] = (float)(ds[g * 26 + 19 + j] * inv_n);
        for (int r = 0; r < 11; ++r) {
            float s = bd[r];
            for (int j = 0; j < 7; ++j) s += hm[j] * Wd[j * 11 + r];
            v[g * 11 + r] = s;
        }
    }
    float h[7], h2[7];
    for (int j = 0; j < 7; ++j) {
        float s = bs0[j];
        for (int k = 0; k < 22; ++k) s += v[k] * Ws0[k * 7 + j];
        h[j] = s;  // no ReLU on first layer (matches reference)
    }
    const float* Ws[3] = {Ws1, Ws2, Ws3};
    const float* bs[3] = {bs1, bs2, bs3};
    for (int l = 0; l < 3; ++l) {
        for (int j = 0; j < 7; ++j) {
            float s = bs[l][j];
            for (int k = 0; k < 7; ++k) s += h[k] * Ws[l][k * 7 + j];
            h2[j] = fmaxf(s, 0.f);
        }
        for (int j = 0; j < 7; ++j) h[j] = h2[j];
    }
    for (int r = 0; r < 12; ++r) {
        float s = bsim[r];
        for (int j = 0; j < 7; ++j) s += h[j] * Wsim[j * 12 + r];
        out[r] = 1.f / (1.f + expf(-s));
    }
}

extern "C" void kernel_launch(void* const* d_in, const int* in_sizes, int n_in,
                              void* d_out, int out_size, void* d_ws, size_t ws_size,
                              hipStream_t stream) {
    const int E = in_sizes[0];
    const int n = NNODES;
    const int* src1 = (const int*)d_in[0];
    const int* dst1 = (const int*)d_in[1];
    const int* src2 = (const int*)d_in[2];
    const int* dst2 = (const int*)d_in[3];
    const float* W_init = (const float*)d_in[5];
    const float* b_init = (const float*)d_in[6];
    const float* Wg  = (const float*)d_in[7];
    const float* bg  = (const float*)d_in[8];
    const float* Wt1 = (const float*)d_in[9];
    const float* g1  = (const float*)d_in[10];
    const float* b1  = (const float*)d_in[11];
    const float* Wt2 = (const float*)d_in[12];
    const float* g2  = (const float*)d_in[13];
    const float* b2  = (const float*)d_in[14];
    const float* Wd  = (const float*)d_in[15];
    const float* bd  = (const float*)d_in[16];
    const float* Ws0 = (const float*)d_in[17];
    const float* bs0 = (const float*)d_in[18];
    const float* Ws1 = (const float*)d_in[19];
    const float* bs1 = (const float*)d_in[20];
    const float* Ws2 = (const float*)d_in[21];
    const float* bs2 = (const float*)d_in[22];
    const float* Ws3 = (const float*)d_in[23];
    const float* bs3 = (const float*)d_in[24];
    const float* Wsim = (const float*)d_in[25];
    const float* bsim = (const float*)d_in[26];

    float* F     = (float*)d_ws;
    float* norm  = F;                      // n   (deg -> norm)
    float* s1    = F + (size_t)n;          // n
    float* s2    = F + 2 * (size_t)n;      // n
    float* s1n   = F + 3 * (size_t)n;      // n
    float* h1n   = F + 4 * (size_t)n;      // 8n  (h1*norm -> f1pn -> x2)
    float* bufA  = F + 12 * (size_t)n;     // 8n  (f1 acc -> f1p)
    float* bufC  = F + 20 * (size_t)n;     // 8n  (f2 acc -> f2p raw)
    float* fscal = F + 28 * (size_t)n;     // 128 floats
    double* dscal = (double*)(F + 28 * (size_t)n + 128);  // 52 doubles (8B-aligned)

    const int ebk = ((E + 3) / 4 + 255) / 256;
    const int nbk = (n + 255) / 256;
    const int rbk = 1024;

    hipMemsetAsync(dscal, 0, 52 * sizeof(double), stream);
    k_t0<<<1, 1, 0, stream>>>(W_init, b_init, Wg, bg, Wt1, fscal);

    for (int g = 0; g < 2; ++g) {
        const int* src = g ? src2 : src1;
        const int* dst = g ? dst2 : dst1;
        float* fsg  = fscal + 28 + g * 35;
        double* dsg = dscal + g * 26;

        hipMemsetAsync(norm, 0, 3 * (size_t)n * sizeof(float), stream);   // norm,s1,s2
        hipMemsetAsync(bufA, 0, 16 * (size_t)n * sizeof(float), stream);  // bufA,bufC

        k_deg<<<ebk, 256, 0, stream>>>(dst, norm, E);
        k_norm<<<nbk, 256, 0, stream>>>(norm, n);
        k_gs<<<ebk, 256, 0, stream>>>(src, dst, norm, s1, E);
        k_s1fin<<<nbk, 256, 0, stream>>>(s1, s1n, norm, n);
        k_gs<<<ebk, 256, 0, stream>>>(src, dst, s1n, s2, E);
        k_s2fin_mom<<<rbk, 256, 0, stream>>>(s2, s1, norm, dsg, n);
        k_t1<<<1, 1, 0, stream>>>(dsg, fscal, g1, b1, fsg);
        k_h1n<<<nbk, 256, 0, stream>>>(s1, s2, norm, fsg, h1n, n);
        k_prop7<<<ebk, 256, 0, stream>>>(src, dst, h1n, bufA, E);
        k_scaleA<<<nbk, 256, 0, stream>>>(norm, bufA, h1n, n);   // h1n becomes f1p*norm
        k_prop7<<<ebk, 256, 0, stream>>>(src, dst, h1n, bufC, E);
        k_x2<<<rbk, 256, 0, stream>>>(s1, s2, norm, fsg, bufA, bufC, Wt2, h1n, dsg, n); // h1n becomes x2
        k_t2<<<1, 1, 0, stream>>>(dsg, g2, b2, fsg);
        k_h2sum<<<rbk, 256, 0, stream>>>(h1n, fsg, dsg, n);
    }
    k_final<<<1, 1, 0, stream>>>(dscal, Wd, bd, Ws0, bs0, Ws1, bs1, Ws2, bs2, Ws3, bs3,
                                 Wsim, bsim, (float*)d_out);
}

// Round 2
// 2833.837 us; speedup vs baseline: 4.8812x; 4.8812x over previous
//
#include <hip/hip_runtime.h>
#include <hip/hip_bf16.h>
#include <math.h>

#define NNODES 500000
#define BN_EPS 1e-5f
#define SCAN_CHUNK 2048
#define NSCAN_BLKS ((NNODES + SCAN_CHUNK - 1) / SCAN_CHUNK)   // 245

__device__ __forceinline__ int atomAddI(int* p, int v) {
    return __hip_atomic_fetch_add(p, v, __ATOMIC_RELAXED, __HIP_MEMORY_SCOPE_AGENT);
}
__device__ __forceinline__ void atomAddD(double* p, double v) {
    __hip_atomic_fetch_add(p, v, __ATOMIC_RELAXED, __HIP_MEMORY_SCOPE_AGENT);
}

// ---------- block-level reduce of CNT doubles, then atomic to dst[0..CNT) ----------
template<int CNT>
__device__ __forceinline__ void blk_reduce_atomic(double (&vals)[CNT], double* dst) {
    __shared__ double sh[CNT][4];
    int lane = threadIdx.x & 63, wid = threadIdx.x >> 6;
#pragma unroll
    for (int k = 0; k < CNT; ++k) {
        double v = vals[k];
#pragma unroll
        for (int o = 32; o; o >>= 1) v += __shfl_down(v, o);
        if (lane == 0) sh[k][wid] = v;
    }
    __syncthreads();
    if ((int)threadIdx.x < CNT) {
        double v = sh[threadIdx.x][0] + sh[threadIdx.x][1] + sh[threadIdx.x][2] + sh[threadIdx.x][3];
        atomAddD(dst + threadIdx.x, v);
    }
}

// ---------- tiny: h_row, a0/a1/a2 from weights only ----------
__global__ void k_t0(const float* __restrict__ Wi, const float* __restrict__ bi,
                     const float* __restrict__ Wg, const float* __restrict__ bg,
                     const float* __restrict__ Wt1, float* __restrict__ fs) {
    if (threadIdx.x || blockIdx.x) return;
    float xr[4];
    for (int j = 0; j < 4; ++j) {
        float s = bi[j];
        for (int k = 0; k < 12; ++k) s += Wi[k * 4 + j];
        xr[j] = s;
    }
    float hr[7];
    for (int j = 0; j < 7; ++j) {
        float s = bg[j];
        for (int k = 0; k < 4; ++k) s += xr[k] * Wg[k * 7 + j];
        hr[j] = 1.f / (1.f + expf(-s));
        fs[j] = hr[j];
    }
    for (int j = 0; j < 7; ++j) {
        float s0 = 0.f, s1 = 0.f, s2 = 0.f;
        for (int k = 0; k < 7; ++k) {
            s0 += hr[k] * Wt1[k * 7 + j];
            s1 += hr[k] * Wt1[(7 + k) * 7 + j];
            s2 += hr[k] * Wt1[(14 + k) * 7 + j];
        }
        fs[7 + j] = s0; fs[14 + j] = s1; fs[21 + j] = s2;
    }
}

// ---------- CSR build: histogram of dst ----------
__global__ void __launch_bounds__(256) k_hist(const int* __restrict__ dst, int* __restrict__ cnt, int E) {
    int i = (blockIdx.x * blockDim.x + threadIdx.x) * 4;
    if (i + 3 < E) {
        int4 d = *reinterpret_cast<const int4*>(dst + i);
        atomAddI(cnt + d.x, 1); atomAddI(cnt + d.y, 1);
        atomAddI(cnt + d.z, 1); atomAddI(cnt + d.w, 1);
    } else {
        for (; i < E; ++i) atomAddI(cnt + dst[i], 1);
    }
}

// ---------- scan A: per-chunk sums ----------
__global__ void __launch_bounds__(256) k_scanA(const int* __restrict__ cnt, int* __restrict__ part, int n) {
    int b = blockIdx.x, t = threadIdx.x;
    int base = b * SCAN_CHUNK + t * 8;
    int s = 0;
#pragma unroll
    for (int j = 0; j < 8; ++j) { int idx = base + j; if (idx < n) s += cnt[idx]; }
    __shared__ int sh[4];
#pragma unroll
    for (int o = 32; o; o >>= 1) s += __shfl_down(s, o);
    int lane = t & 63, wid = t >> 6;
    if (lane == 0) sh[wid] = s;
    __syncthreads();
    if (t == 0) part[b] = sh[0] + sh[1] + sh[2] + sh[3];
}

// ---------- scan B: exclusive scan of partials (single block) ----------
__global__ void __launch_bounds__(256) k_scanB(int* __restrict__ part) {
    int t = threadIdx.x;
    int v = (t < NSCAN_BLKS) ? part[t] : 0;
    __shared__ int sh[256];
    sh[t] = v; __syncthreads();
    for (int o = 1; o < 256; o <<= 1) {
        int x = (t >= o) ? sh[t - o] : 0;
        __syncthreads();
        sh[t] += x;
        __syncthreads();
    }
    if (t < NSCAN_BLKS) part[t] = sh[t] - v;   // exclusive
}

// ---------- scan C: write row starts (rp) + norm ----------
__global__ void __launch_bounds__(256) k_scanC(const int* __restrict__ cnt, const int* __restrict__ part,
                                               int* __restrict__ rp, float* __restrict__ nrm, int n) {
    int b = blockIdx.x, t = threadIdx.x;
    int base = b * SCAN_CHUNK + t * 8;
    int c[8]; int s = 0;
#pragma unroll
    for (int j = 0; j < 8; ++j) { int idx = base + j; c[j] = (idx < n) ? cnt[idx] : 0; s += c[j]; }
    __shared__ int sh[256];
    sh[t] = s; __syncthreads();
    for (int o = 1; o < 256; o <<= 1) {
        int x = (t >= o) ? sh[t - o] : 0;
        __syncthreads();
        sh[t] += x;
        __syncthreads();
    }
    int run = part[b] + sh[t] - s;   // exclusive across block
#pragma unroll
    for (int j = 0; j < 8; ++j) {
        int idx = base + j;
        if (idx < n) {
            rp[idx] = run;
            nrm[idx] = rsqrtf((float)(c[j] > 0 ? c[j] : 1));
            run += c[j];
        }
    }
}

// ---------- CSR fill: rp used as cursor; after this rp[i] = end of row i ----------
__global__ void __launch_bounds__(256) k_fill(const int* __restrict__ src, const int* __restrict__ dst,
                                              int* __restrict__ rp, int* __restrict__ col, int E) {
    int i = (blockIdx.x * blockDim.x + threadIdx.x) * 4;
    if (i + 3 < E) {
        int4 s = *reinterpret_cast<const int4*>(src + i);
        int4 d = *reinterpret_cast<const int4*>(dst + i);
        col[atomAddI(rp + d.x, 1)] = s.x;
        col[atomAddI(rp + d.y, 1)] = s.y;
        col[atomAddI(rp + d.z, 1)] = s.z;
        col[atomAddI(rp + d.w, 1)] = s.w;
    } else {
        for (; i < E; ++i) col[atomAddI(rp + dst[i], 1)] = src[i];
    }
}

// ---------- gather: s1 = norm * sum(norm[src]); s1n = s1*norm ----------
__global__ void __launch_bounds__(256) k_s1g(const int* __restrict__ rp, const int* __restrict__ col,
                                             const float* __restrict__ nrm, float* __restrict__ s1,
                                             float* __restrict__ s1n, int n) {
    int i = blockIdx.x * blockDim.x + threadIdx.x;
    if (i >= n) return;
    int b = i ? rp[i - 1] : 0, e = rp[i];
    float s = 0.f;
    for (int k = b; k < e; ++k) s += nrm[col[k]];
    float v = s * nrm[i];
    s1[i] = v; s1n[i] = v * nrm[i];
}

// ---------- gather: s2 = norm * sum(s1n[src]); + moments of (s1,s2) ----------
__global__ void __launch_bounds__(256) k_s2g(const int* __restrict__ rp, const int* __restrict__ col,
                                             const float* __restrict__ nrm, const float* __restrict__ s1,
                                             const float* __restrict__ s1n, float* __restrict__ s2,
                                             double* __restrict__ ds, int n) {
    double acc[5] = {0, 0, 0, 0, 0};
    for (int i = blockIdx.x * blockDim.x + threadIdx.x; i < n; i += gridDim.x * blockDim.x) {
        int b = i ? rp[i - 1] : 0, e = rp[i];
        float s = 0.f;
        for (int k = b; k < e; ++k) s += s1n[col[k]];
        float v2 = s * nrm[i];
        s2[i] = v2;
        float v1 = s1[i];
        acc[0] += v1; acc[1] += v2;
        acc[2] += (double)v1 * (double)v1;
        acc[3] += (double)v2 * (double)v2;
        acc[4] += (double)v1 * (double)v2;
    }
    blk_reduce_atomic<5>(acc, ds);
}

// ---------- tiny: BN1 folded coefficients d0,d1,d2 ----------
__global__ void k_t1(const double* __restrict__ ds, const float* __restrict__ fs,
                     const float* __restrict__ g1, const float* __restrict__ b1, float* __restrict__ fsg) {
    if (threadIdx.x || blockIdx.x) return;
    const double inv_n = 1.0 / (double)NNODES;
    float mu1 = (float)(ds[0] * inv_n), mu2 = (float)(ds[1] * inv_n);
    float V11 = (float)(ds[2] * inv_n) - mu1 * mu1;
    float V22 = (float)(ds[3] * inv_n) - mu2 * mu2;
    float V12 = (float)(ds[4] * inv_n) - mu1 * mu2;
    for (int j = 0; j < 7; ++j) {
        float a1 = fs[14 + j], a2 = fs[21 + j];
        float var = a1 * a1 * V11 + a2 * a2 * V22 + 2.f * a1 * a2 * V12;
        float ig = (1.f / sqrtf(var + BN_EPS)) * g1[j];
        fsg[j]      = b1[j] - (mu1 * a1 + mu2 * a2) * ig;  // d0
        fsg[7 + j]  = a1 * ig;                              // d1
        fsg[14 + j] = a2 * ig;                              // d2
    }
}

// ---------- node: h1n = relu(d0 + s1*d1 + s2*d2) * norm, stride-8 padded ----------
__global__ void __launch_bounds__(256) k_h1n(const float* __restrict__ s1, const float* __restrict__ s2,
                                             const float* __restrict__ nrm, const float* __restrict__ fsg,
                                             float* __restrict__ h1n, int n) {
    int i = blockIdx.x * blockDim.x + threadIdx.x;
    if (i >= n) return;
    float S1 = s1[i], S2 = s2[i], Nn = nrm[i];
    float o[8];
#pragma unroll
    for (int j = 0; j < 7; ++j)
        o[j] = fmaxf(fsg[j] + S1 * fsg[7 + j] + S2 * fsg[14 + j], 0.f) * Nn;
    o[7] = 0.f;
    float4* q = reinterpret_cast<float4*>(h1n + (size_t)i * 8);
    q[0] = make_float4(o[0], o[1], o[2], o[3]);
    q[1] = make_float4(o[4], o[5], o[6], o[7]);
}

// ---------- gather: f1n = (norm^2 * sum h1n[src]) = f1p*norm, stride-8 ----------
__global__ void __launch_bounds__(256) k_f1g(const int* __restrict__ rp, const int* __restrict__ col,
                                             const float* __restrict__ nrm, const float* __restrict__ h1n,
                                             float* __restrict__ f1n, int n) {
    int i = blockIdx.x * blockDim.x + threadIdx.x;
    if (i >= n) return;
    int b = i ? rp[i - 1] : 0, e = rp[i];
    float a0 = 0, a1 = 0, a2 = 0, a3 = 0, a4 = 0, a5 = 0, a6 = 0;
    for (int k = b; k < e; ++k) {
        const float4* p = reinterpret_cast<const float4*>(h1n + (size_t)col[k] * 8);
        float4 x = p[0], y = p[1];
        a0 += x.x; a1 += x.y; a2 += x.z; a3 += x.w;
        a4 += y.x; a5 += y.y; a6 += y.z;
    }
    float Nn = nrm[i], s = Nn * Nn;
    float4* q = reinterpret_cast<float4*>(f1n + (size_t)i * 8);
    q[0] = make_float4(a0 * s, a1 * s, a2 * s, a3 * s);
    q[1] = make_float4(a4 * s, a5 * s, a6 * s, 0.f);
}

// ---------- fused: f2p gather + x2 = [h1|f1p|f2p]@Wt2 + BN2 moments ----------
__global__ void __launch_bounds__(256) k_x2f(const int* __restrict__ rp, const int* __restrict__ col,
                                             const int* __restrict__ cnt,
                                             const float* __restrict__ s1, const float* __restrict__ s2,
                                             const float* __restrict__ nrm, const float* __restrict__ fsg,
                                             const float* __restrict__ f1n, const float* __restrict__ Wt2,
                                             float* __restrict__ x2o, double* __restrict__ ds, int n) {
    __shared__ float w[147];
    for (int k = threadIdx.x; k < 147; k += blockDim.x) w[k] = Wt2[k];
    float dc[21];
#pragma unroll
    for (int j = 0; j < 21; ++j) dc[j] = fsg[j];
    __syncthreads();
    double sx[7] = {0, 0, 0, 0, 0, 0, 0}, sq[7] = {0, 0, 0, 0, 0, 0, 0};
    for (int i = blockIdx.x * blockDim.x + threadIdx.x; i < n; i += gridDim.x * blockDim.x) {
        int b = i ? rp[i - 1] : 0, e = rp[i];
        float g0 = 0, g1 = 0, g2 = 0, g3 = 0, g4 = 0, g5 = 0, g6 = 0;
        for (int k = b; k < e; ++k) {
            const float4* p = reinterpret_cast<const float4*>(f1n + (size_t)col[k] * 8);
            float4 x = p[0], y = p[1];
            g0 += x.x; g1 += x.y; g2 += x.z; g3 += x.w;
            g4 += y.x; g5 += y.y; g6 += y.z;
        }
        float S1 = s1[i], S2 = s2[i], Nn = nrm[i];
        float rn = sqrtf((float)(cnt[i] > 0 ? cnt[i] : 1));   // 1/norm
        float h1[7];
#pragma unroll
        for (int k = 0; k < 7; ++k) h1[k] = fmaxf(dc[k] + S1 * dc[7 + k] + S2 * dc[14 + k], 0.f);
        const float4* pf = reinterpret_cast<const float4*>(f1n + (size_t)i * 8);
        float4 fa = pf[0], fb = pf[1];
        float f1p[7] = {fa.x * rn, fa.y * rn, fa.z * rn, fa.w * rn, fb.x * rn, fb.y * rn, fb.z * rn};
        float f2p[7] = {g0 * Nn, g1 * Nn, g2 * Nn, g3 * Nn, g4 * Nn, g5 * Nn, g6 * Nn};
        float x2[8];
#pragma unroll
        for (int j = 0; j < 7; ++j) {
            float s = 0.f;
#pragma unroll
            for (int k = 0; k < 7; ++k)
                s += h1[k] * w[k * 7 + j] + f1p[k] * w[(7 + k) * 7 + j] + f2p[k] * w[(14 + k) * 7 + j];
            x2[j] = s;
            sx[j] += s; sq[j] += (double)s * (double)s;
        }
        x2[7] = 0.f;
        float4* q = reinterpret_cast<float4*>(x2o + (size_t)i * 8);
        q[0] = make_float4(x2[0], x2[1], x2[2], x2[3]);
        q[1] = make_float4(x2[4], x2[5], x2[6], x2[7]);
    }
    double acc[14];
#pragma unroll
    for (int j = 0; j < 7; ++j) { acc[j] = sx[j]; acc[7 + j] = sq[j]; }
    blk_reduce_atomic<14>(acc, ds + 5);
}

// ---------- tiny: BN2 folded coefficients c0,c1 ----------
__global__ void k_t2(const double* __restrict__ ds, const float* __restrict__ g2,
                     const float* __restrict__ b2, float* __restrict__ fsg) {
    if (threadIdx.x || blockIdx.x) return;
    const double inv_n = 1.0 / (double)NNODES;
    for (int j = 0; j < 7; ++j) {
        float m = (float)(ds[5 + j] * inv_n);
        float v = (float)(ds[12 + j] * inv_n) - m * m;
        float ig = (1.f / sqrtf(v + BN_EPS)) * g2[j];
        fsg[21 + j] = b2[j] - m * ig;  // c0
        fsg[28 + j] = ig;              // c1
    }
}

// ---------- node: h2 column sums ----------
__global__ void __launch_bounds__(256) k_h2sum(const float* __restrict__ x2o, const float* __restrict__ fsg,
                                               double* __restrict__ ds, int n) {
    float c0[7], c1[7];
#pragma unroll
    for (int j = 0; j < 7; ++j) { c0[j] = fsg[21 + j]; c1[j] = fsg[28 + j]; }
    double acc[7] = {0, 0, 0, 0, 0, 0, 0};
    for (int i = blockIdx.x * blockDim.x + threadIdx.x; i < n; i += gridDim.x * blockDim.x) {
        const float4* p = reinterpret_cast<const float4*>(x2o + (size_t)i * 8);
        float4 a = p[0], b = p[1];
        float x[7] = {a.x, a.y, a.z, a.w, b.x, b.y, b.z};
#pragma unroll
        for (int j = 0; j < 7; ++j) acc[j] += (double)fmaxf(x[j] * c1[j] + c0[j], 0.f);
    }
    blk_reduce_atomic<7>(acc, ds + 19);
}

// ---------- tiny: embeddings + similarity MLP + sigmoid ----------
__global__ void k_final(const double* __restrict__ ds, const float* __restrict__ Wd, const float* __restrict__ bd,
                        const float* __restrict__ Ws0, const float* __restrict__ bs0,
                        const float* __restrict__ Ws1, const float* __restrict__ bs1,
                        const float* __restrict__ Ws2, const float* __restrict__ bs2,
                        const float* __restrict__ Ws3, const float* __restrict__ bs3,
                        const float* __restrict__ Wsim, const float* __restrict__ bsim,
                        float* __restrict__ out) {
    if (threadIdx.x || blockIdx.x) return;
    const double inv_n = 1.0 / (double)NNODES;
    float v[22];
    for (int g = 0; g < 2; ++g) {
        float hm[7];
        for (int j = 0; j < 7; ++j) hm[j] = (float)(ds[g * 26 + 19 + j] * inv_n);
        for (int r = 0; r < 11; ++r) {
            float s = bd[r];
            for (int j = 0; j < 7; ++j) s += hm[j] * Wd[j * 11 + r];
            v[g * 11 + r] = s;
        }
    }
    float h[7], h2[7];
    for (int j = 0; j < 7; ++j) {
        float s = bs0[j];
        for (int k = 0; k < 22; ++k) s += v[k] * Ws0[k * 7 + j];
        h[j] = s;
    }
    const float* Ws[3] = {Ws1, Ws2, Ws3};
    const float* bs[3] = {bs1, bs2, bs3};
    for (int l = 0; l < 3; ++l) {
        for (int j = 0; j < 7; ++j) {
            float s = bs[l][j];
            for (int k = 0; k < 7; ++k) s += h[k] * Ws[l][k * 7 + j];
            h2[j] = fmaxf(s, 0.f);
        }
        for (int j = 0; j < 7; ++j) h[j] = h2[j];
    }
    for (int r = 0; r < 12; ++r) {
        float s = bsim[r];
        for (int j = 0; j < 7; ++j) s += h[j] * Wsim[j * 12 + r];
        out[r] = 1.f / (1.f + expf(-s));
    }
}

extern "C" void kernel_launch(void* const* d_in, const int* in_sizes, int n_in,
                              void* d_out, int out_size, void* d_ws, size_t ws_size,
                              hipStream_t stream) {
    const int E = in_sizes[0];
    const int n = NNODES;
    const int* src1 = (const int*)d_in[0];
    const int* dst1 = (const int*)d_in[1];
    const int* src2 = (const int*)d_in[2];
    const int* dst2 = (const int*)d_in[3];
    const float* W_init = (const float*)d_in[5];
    const float* b_init = (const float*)d_in[6];
    const float* Wg  = (const float*)d_in[7];
    const float* bg  = (const float*)d_in[8];
    const float* Wt1 = (const float*)d_in[9];
    const float* g1  = (const float*)d_in[10];
    const float* b1  = (const float*)d_in[11];
    const float* Wt2 = (const float*)d_in[12];
    const float* g2  = (const float*)d_in[13];
    const float* b2  = (const float*)d_in[14];
    const float* Wd  = (const float*)d_in[15];
    const float* bd  = (const float*)d_in[16];
    const float* Ws0 = (const float*)d_in[17];
    const float* bs0 = (const float*)d_in[18];
    const float* Ws1 = (const float*)d_in[19];
    const float* bs1 = (const float*)d_in[20];
    const float* Ws2 = (const float*)d_in[21];
    const float* bs2 = (const float*)d_in[22];
    const float* Ws3 = (const float*)d_in[23];
    const float* bs3 = (const float*)d_in[24];
    const float* Wsim = (const float*)d_in[25];
    const float* bsim = (const float*)d_in[26];

    // workspace layout (floats unless noted); total ≈ 22n + E + small ≈ 77 MB
    float* F     = (float*)d_ws;
    float* norm  = F;                       // n
    float* s1    = F + (size_t)n;           // n
    float* s2    = F + 2 * (size_t)n;       // n
    float* s1n   = F + 3 * (size_t)n;       // n
    float* h1n   = F + 4 * (size_t)n;       // 8n  (h1*norm; later x2o)
    float* f1n   = F + 12 * (size_t)n;      // 8n  (f1p*norm)
    int*   cnt   = (int*)(F + 20 * (size_t)n);          // n
    int*   rp    = (int*)(F + 21 * (size_t)n);          // n  (row starts -> cursors -> row ends)
    int*   part  = (int*)(F + 22 * (size_t)n);          // 256
    int*   col   = (int*)(F + 22 * (size_t)n + 256);    // E
    float* fscal = F + 22 * (size_t)n + 256 + (size_t)E;        // 128
    double* dscal = (double*)(fscal + 128);                     // 52 doubles

    const int ebk4 = ((E + 3) / 4 + 255) / 256;
    const int nbk  = (n + 255) / 256;
    const int rbk  = 1024;

    hipMemsetAsync(dscal, 0, 52 * sizeof(double), stream);
    k_t0<<<1, 1, 0, stream>>>(W_init, b_init, Wg, bg, Wt1, fscal);

    for (int g = 0; g < 2; ++g) {
        const int* src = g ? src2 : src1;
        const int* dst = g ? dst2 : dst1;
        float* fsg  = fscal + 28 + g * 35;
        double* dsg = dscal + g * 26;

        hipMemsetAsync(cnt, 0, (size_t)n * sizeof(int), stream);
        k_hist <<<ebk4, 256, 0, stream>>>(dst, cnt, E);
        k_scanA<<<NSCAN_BLKS, 256, 0, stream>>>(cnt, part, n);
        k_scanB<<<1, 256, 0, stream>>>(part);
        k_scanC<<<NSCAN_BLKS, 256, 0, stream>>>(cnt, part, rp, norm, n);
        k_fill <<<ebk4, 256, 0, stream>>>(src, dst, rp, col, E);

        k_s1g<<<nbk, 256, 0, stream>>>(rp, col, norm, s1, s1n, n);
        k_s2g<<<rbk, 256, 0, stream>>>(rp, col, norm, s1, s1n, s2, dsg, n);
        k_t1<<<1, 1, 0, stream>>>(dsg, fscal, g1, b1, fsg);
        k_h1n<<<nbk, 256, 0, stream>>>(s1, s2, norm, fsg, h1n, n);
        k_f1g<<<nbk, 256, 0, stream>>>(rp, col, norm, h1n, f1n, n);
        k_x2f<<<rbk, 256, 0, stream>>>(rp, col, cnt, s1, s2, norm, fsg, f1n, Wt2, h1n, dsg, n);
        k_t2<<<1, 1, 0, stream>>>(dsg, g2, b2, fsg);
        k_h2sum<<<rbk, 256, 0, stream>>>(h1n, fsg, dsg, n);
    }
    k_final<<<1, 1, 0, stream>>>(dscal, Wd, bd, Ws0, bs0, Ws1, bs1, Ws2, bs2, Ws3, bs3,
                                 Wsim, bsim, (float*)d_out);
}

// Round 4
// 2053.482 us; speedup vs baseline: 6.7361x; 1.3800x over previous
//
#include <hip/hip_runtime.h>
#include <hip/hip_bf16.h>
#include <math.h>

#define NNODES 500000
#define BN_EPS 1e-5f
#define BKT 512
#define NBKT ((NNODES + BKT - 1) / BKT)          // 977
#define EPB 16384                                 // edges per block in hist/scatter

__device__ __forceinline__ int atomAddI(int* p, int v) {
    return __hip_atomic_fetch_add(p, v, __ATOMIC_RELAXED, __HIP_MEMORY_SCOPE_AGENT);
}
__device__ __forceinline__ void atomAddD(double* p, double v) {
    __hip_atomic_fetch_add(p, v, __ATOMIC_RELAXED, __HIP_MEMORY_SCOPE_AGENT);
}
__device__ __forceinline__ void ldsAddF(float* p, float v) {
    __hip_atomic_fetch_add(p, v, __ATOMIC_RELAXED, __HIP_MEMORY_SCOPE_WORKGROUP);
}

// ---------- block-level reduce of CNT doubles, then atomic to dst[0..CNT) ----------
template<int CNT>
__device__ __forceinline__ void blk_reduce_atomic(double (&vals)[CNT], double* dst) {
    __shared__ double sh[CNT][4];
    int lane = threadIdx.x & 63, wid = threadIdx.x >> 6;
#pragma unroll
    for (int k = 0; k < CNT; ++k) {
        double v = vals[k];
#pragma unroll
        for (int o = 32; o; o >>= 1) v += __shfl_down(v, o);
        if (lane == 0) sh[k][wid] = v;
    }
    __syncthreads();
    if ((int)threadIdx.x < CNT) {
        double v = sh[threadIdx.x][0] + sh[threadIdx.x][1] + sh[threadIdx.x][2] + sh[threadIdx.x][3];
        atomAddD(dst + threadIdx.x, v);
    }
}

// ---------- tiny: h_row, a0/a1/a2 from weights only ----------
__global__ void k_t0(const float* __restrict__ Wi, const float* __restrict__ bi,
                     const float* __restrict__ Wg, const float* __restrict__ bg,
                     const float* __restrict__ Wt1, float* __restrict__ fs) {
    if (threadIdx.x || blockIdx.x) return;
    float xr[4];
    for (int j = 0; j < 4; ++j) {
        float s = bi[j];
        for (int k = 0; k < 12; ++k) s += Wi[k * 4 + j];
        xr[j] = s;
    }
    float hr[7];
    for (int j = 0; j < 7; ++j) {
        float s = bg[j];
        for (int k = 0; k < 4; ++k) s += xr[k] * Wg[k * 7 + j];
        hr[j] = 1.f / (1.f + expf(-s));
        fs[j] = hr[j];
    }
    for (int j = 0; j < 7; ++j) {
        float s0 = 0.f, s1 = 0.f, s2 = 0.f;
        for (int k = 0; k < 7; ++k) {
            s0 += hr[k] * Wt1[k * 7 + j];
            s1 += hr[k] * Wt1[(7 + k) * 7 + j];
            s2 += hr[k] * Wt1[(14 + k) * 7 + j];
        }
        fs[7 + j] = s0; fs[14 + j] = s1; fs[21 + j] = s2;
    }
}

// ---------- bucket histogram (LDS-privatized) ----------
__global__ void __launch_bounds__(256) k_bhist(const int* __restrict__ dst, int* __restrict__ gcnt, int E) {
    __shared__ int h[NBKT];
    for (int i = threadIdx.x; i < NBKT; i += 256) h[i] = 0;
    __syncthreads();
    int base = blockIdx.x * EPB;
#pragma unroll
    for (int k = 0; k < EPB / 1024; ++k) {
        int i4 = base + (k * 256 + threadIdx.x) * 4;
        if (i4 + 3 < E) {
            int4 d = *reinterpret_cast<const int4*>(dst + i4);
            atomicAdd(&h[d.x >> 9], 1); atomicAdd(&h[d.y >> 9], 1);
            atomicAdd(&h[d.z >> 9], 1); atomicAdd(&h[d.w >> 9], 1);
        } else {
            for (int i = i4; i < E && i < i4 + 4; ++i) atomicAdd(&h[dst[i] >> 9], 1);
        }
    }
    __syncthreads();
    for (int i = threadIdx.x; i < NBKT; i += 256)
        if (h[i]) atomAddI(gcnt + i, h[i]);
}

// ---------- exclusive scan of bucket counts (1 block, 1024 thr) ----------
__global__ void __launch_bounds__(1024) k_bscan(const int* __restrict__ gcnt,
                                                int* __restrict__ bb, int* __restrict__ gcur) {
    __shared__ int sh[1024];
    int t = threadIdx.x;
    int v = (t < NBKT) ? gcnt[t] : 0;
    sh[t] = v; __syncthreads();
    for (int o = 1; o < 1024; o <<= 1) {
        int x = (t >= o) ? sh[t - o] : 0;
        __syncthreads();
        sh[t] += x;
        __syncthreads();
    }
    if (t < NBKT) { int ex = sh[t] - v; bb[t] = ex; gcur[t] = ex; }
    if (t == 0) bb[NBKT] = sh[1023];
}

// ---------- multisplit scatter: packed (dl<<19 | src) ----------
__global__ void __launch_bounds__(256) k_bscat(const int* __restrict__ src, const int* __restrict__ dst,
                                               int* __restrict__ gcur, unsigned int* __restrict__ pairs, int E) {
    __shared__ int h[NBKT];
    for (int i = threadIdx.x; i < NBKT; i += 256) h[i] = 0;
    __syncthreads();
    int base = blockIdx.x * EPB;
    // phase 1: count
#pragma unroll
    for (int k = 0; k < EPB / 1024; ++k) {
        int i4 = base + (k * 256 + threadIdx.x) * 4;
        if (i4 + 3 < E) {
            int4 d = *reinterpret_cast<const int4*>(dst + i4);
            atomicAdd(&h[d.x >> 9], 1); atomicAdd(&h[d.y >> 9], 1);
            atomicAdd(&h[d.z >> 9], 1); atomicAdd(&h[d.w >> 9], 1);
        } else {
            for (int i = i4; i < E && i < i4 + 4; ++i) atomicAdd(&h[dst[i] >> 9], 1);
        }
    }
    __syncthreads();
    // phase 2: reserve contiguous slots per bucket for this block
    for (int i = threadIdx.x; i < NBKT; i += 256) {
        int c = h[i];
        h[i] = c ? atomAddI(gcur + i, c) : 0;
    }
    __syncthreads();
    // phase 3: rank & write
#pragma unroll
    for (int k = 0; k < EPB / 1024; ++k) {
        int i4 = base + (k * 256 + threadIdx.x) * 4;
        if (i4 + 3 < E) {
            int4 s = *reinterpret_cast<const int4*>(src + i4);
            int4 d = *reinterpret_cast<const int4*>(dst + i4);
            int se[4] = {s.x, s.y, s.z, s.w};
            int de[4] = {d.x, d.y, d.z, d.w};
#pragma unroll
            for (int e = 0; e < 4; ++e) {
                int b = de[e] >> 9;
                int pos = atomicAdd(&h[b], 1);
                pairs[pos] = ((unsigned int)(de[e] & 511) << 19) | (unsigned int)se[e];
            }
        } else {
            for (int i = i4; i < E && i < i4 + 4; ++i) {
                int b = dst[i] >> 9;
                int pos = atomicAdd(&h[b], 1);
                pairs[pos] = ((unsigned int)(dst[i] & 511) << 19) | (unsigned int)src[i];
            }
        }
    }
}

// ---------- per-bucket: degree -> norm, sdeg ----------
__global__ void __launch_bounds__(256) k_deg(const unsigned int* __restrict__ pairs, const int* __restrict__ bb,
                                             float* __restrict__ nrm, float* __restrict__ sdeg, int n) {
    __shared__ int deg[BKT];
    int b = blockIdx.x, t = threadIdx.x;
    deg[t] = 0; deg[t + 256] = 0;
    __syncthreads();
    int lo = bb[b], hi = bb[b + 1];
    for (int k = lo + t; k < hi; k += 256) atomicAdd(&deg[pairs[k] >> 19], 1);
    __syncthreads();
#pragma unroll
    for (int j = 0; j < 2; ++j) {
        int dl = t + j * 256, node = b * BKT + dl;
        if (node < n) {
            float sd = sqrtf((float)(deg[dl] > 0 ? deg[dl] : 1));
            sdeg[node] = sd;
            nrm[node] = 1.f / sd;
        }
    }
}

// ---------- per-bucket: s1 = norm * sum norm[src]; s1n = s1*norm ----------
__global__ void __launch_bounds__(256) k_s1(const unsigned int* __restrict__ pairs, const int* __restrict__ bb,
                                            const float* __restrict__ nrm, float* __restrict__ s1,
                                            float* __restrict__ s1n, int n) {
    __shared__ float acc[BKT];
    int b = blockIdx.x, t = threadIdx.x;
    acc[t] = 0.f; acc[t + 256] = 0.f;
    __syncthreads();
    int lo = bb[b], hi = bb[b + 1];
    for (int k = lo + t; k < hi; k += 256) {
        unsigned int v = pairs[k];
        ldsAddF(&acc[v >> 19], nrm[v & 0x7FFFF]);
    }
    __syncthreads();
#pragma unroll
    for (int j = 0; j < 2; ++j) {
        int dl = t + j * 256, node = b * BKT + dl;
        if (node < n) {
            float nn = nrm[node], v1 = acc[dl] * nn;
            s1[node] = v1; s1n[node] = v1 * nn;
        }
    }
}

// ---------- per-bucket: s2 = norm * sum s1n[src]; + moments of (s1,s2) ----------
__global__ void __launch_bounds__(256) k_s2(const unsigned int* __restrict__ pairs, const int* __restrict__ bb,
                                            const float* __restrict__ nrm, const float* __restrict__ s1,
                                            const float* __restrict__ s1n, float* __restrict__ s2,
                                            double* __restrict__ ds, int n) {
    __shared__ float acc[BKT];
    int b = blockIdx.x, t = threadIdx.x;
    acc[t] = 0.f; acc[t + 256] = 0.f;
    __syncthreads();
    int lo = bb[b], hi = bb[b + 1];
    for (int k = lo + t; k < hi; k += 256) {
        unsigned int v = pairs[k];
        ldsAddF(&acc[v >> 19], s1n[v & 0x7FFFF]);
    }
    __syncthreads();
    double m[5] = {0, 0, 0, 0, 0};
#pragma unroll
    for (int j = 0; j < 2; ++j) {
        int dl = t + j * 256, node = b * BKT + dl;
        if (node < n) {
            float nn = nrm[node], v2 = acc[dl] * nn;
            s2[node] = v2;
            float v1 = s1[node];
            m[0] += v1; m[1] += v2;
            m[2] += (double)v1 * (double)v1;
            m[3] += (double)v2 * (double)v2;
            m[4] += (double)v1 * (double)v2;
        }
    }
    blk_reduce_atomic<5>(m, ds);
}

// ---------- tiny: BN1 folded coefficients d0,d1,d2 ----------
__global__ void k_t1(const double* __restrict__ ds, const float* __restrict__ fs,
                     const float* __restrict__ g1, const float* __restrict__ b1, float* __restrict__ fsg) {
    if (threadIdx.x || blockIdx.x) return;
    const double inv_n = 1.0 / (double)NNODES;
    float mu1 = (float)(ds[0] * inv_n), mu2 = (float)(ds[1] * inv_n);
    float V11 = (float)(ds[2] * inv_n) - mu1 * mu1;
    float V22 = (float)(ds[3] * inv_n) - mu2 * mu2;
    float V12 = (float)(ds[4] * inv_n) - mu1 * mu2;
    for (int j = 0; j < 7; ++j) {
        float a1 = fs[14 + j], a2 = fs[21 + j];
        float var = a1 * a1 * V11 + a2 * a2 * V22 + 2.f * a1 * a2 * V12;
        float ig = (1.f / sqrtf(var + BN_EPS)) * g1[j];
        fsg[j]      = b1[j] - (mu1 * a1 + mu2 * a2) * ig;  // d0
        fsg[7 + j]  = a1 * ig;                              // d1
        fsg[14 + j] = a2 * ig;                              // d2
    }
}

// ---------- node: h1n = relu(d0 + s1*d1 + s2*d2) * norm, stride-8 padded ----------
__global__ void __launch_bounds__(256) k_h1n(const float* __restrict__ s1, const float* __restrict__ s2,
                                             const float* __restrict__ nrm, const float* __restrict__ fsg,
                                             float* __restrict__ h1n, int n) {
    int i = blockIdx.x * blockDim.x + threadIdx.x;
    if (i >= n) return;
    float S1 = s1[i], S2 = s2[i], Nn = nrm[i];
    float o[8];
#pragma unroll
    for (int j = 0; j < 7; ++j)
        o[j] = fmaxf(fsg[j] + S1 * fsg[7 + j] + S2 * fsg[14 + j], 0.f) * Nn;
    o[7] = 0.f;
    float4* q = reinterpret_cast<float4*>(h1n + (size_t)i * 8);
    q[0] = make_float4(o[0], o[1], o[2], o[3]);
    q[1] = make_float4(o[4], o[5], o[6], o[7]);
}

// ---------- per-bucket 7-wide: f1n = norm^2 * sum h1n[src] ----------
__global__ void __launch_bounds__(256) k_f1(const unsigned int* __restrict__ pairs, const int* __restrict__ bb,
                                            const float* __restrict__ nrm, const float* __restrict__ h1n,
                                            float* __restrict__ f1n, int n) {
    __shared__ float a[7][BKT];
    int b = blockIdx.x, t = threadIdx.x;
#pragma unroll
    for (int j = 0; j < 7; ++j) { a[j][t] = 0.f; a[j][t + 256] = 0.f; }
    __syncthreads();
    int lo = bb[b], hi = bb[b + 1];
    for (int k = lo + t; k < hi; k += 256) {
        unsigned int v = pairs[k];
        int s = v & 0x7FFFF, dl = v >> 19;
        const float4* p = reinterpret_cast<const float4*>(h1n + (size_t)s * 8);
        float4 x = p[0], y = p[1];
        ldsAddF(&a[0][dl], x.x); ldsAddF(&a[1][dl], x.y); ldsAddF(&a[2][dl], x.z);
        ldsAddF(&a[3][dl], x.w); ldsAddF(&a[4][dl], y.x); ldsAddF(&a[5][dl], y.y);
        ldsAddF(&a[6][dl], y.z);
    }
    __syncthreads();
#pragma unroll
    for (int j = 0; j < 2; ++j) {
        int dl = t + j * 256, node = b * BKT + dl;
        if (node < n) {
            float nn = nrm[node], sc = nn * nn;
            float4* q = reinterpret_cast<float4*>(f1n + (size_t)node * 8);
            q[0] = make_float4(a[0][dl] * sc, a[1][dl] * sc, a[2][dl] * sc, a[3][dl] * sc);
            q[1] = make_float4(a[4][dl] * sc, a[5][dl] * sc, a[6][dl] * sc, 0.f);
        }
    }
}

// ---------- per-bucket fused: f2 gather + x2 = [h1|f1p|f2p]@Wt2 + BN2 moments ----------
__global__ void __launch_bounds__(256) k_x2f(const unsigned int* __restrict__ pairs, const int* __restrict__ bb,
                                             const float* __restrict__ nrm, const float* __restrict__ sdeg,
                                             const float* __restrict__ s1, const float* __restrict__ s2,
                                             const float* __restrict__ fsg, const float* __restrict__ f1n,
                                             const float* __restrict__ Wt2, float* __restrict__ x2o,
                                             double* __restrict__ ds, int n) {
    __shared__ float a[7][BKT];
    __shared__ float w[147];
    int b = blockIdx.x, t = threadIdx.x;
    for (int k = t; k < 147; k += 256) w[k] = Wt2[k];
    float dc[21];
#pragma unroll
    for (int j = 0; j < 21; ++j) dc[j] = fsg[j];
#pragma unroll
    for (int j = 0; j < 7; ++j) { a[j][t] = 0.f; a[j][t + 256] = 0.f; }
    __syncthreads();
    int lo = bb[b], hi = bb[b + 1];
    for (int k = lo + t; k < hi; k += 256) {
        unsigned int v = pairs[k];
        int s = v & 0x7FFFF, dl = v >> 19;
        const float4* p = reinterpret_cast<const float4*>(f1n + (size_t)s * 8);
        float4 x = p[0], y = p[1];
        ldsAddF(&a[0][dl], x.x); ldsAddF(&a[1][dl], x.y); ldsAddF(&a[2][dl], x.z);
        ldsAddF(&a[3][dl], x.w); ldsAddF(&a[4][dl], y.x); ldsAddF(&a[5][dl], y.y);
        ldsAddF(&a[6][dl], y.z);
    }
    __syncthreads();
    double sx[7] = {0, 0, 0, 0, 0, 0, 0}, sq[7] = {0, 0, 0, 0, 0, 0, 0};
#pragma unroll
    for (int jj = 0; jj < 2; ++jj) {
        int dl = t + jj * 256, node = b * BKT + dl;
        if (node < n) {
            float S1 = s1[node], S2 = s2[node], Nn = nrm[node], rn = sdeg[node];
            float h1[7];
#pragma unroll
            for (int k = 0; k < 7; ++k) h1[k] = fmaxf(dc[k] + S1 * dc[7 + k] + S2 * dc[14 + k], 0.f);
            const float4* pf = reinterpret_cast<const float4*>(f1n + (size_t)node * 8);
            float4 fa = pf[0], fb = pf[1];
            float f1p[7] = {fa.x * rn, fa.y * rn, fa.z * rn, fa.w * rn, fb.x * rn, fb.y * rn, fb.z * rn};
            float f2p[7];
#pragma unroll
            for (int k = 0; k < 7; ++k) f2p[k] = a[k][dl] * Nn;
            float x2[8];
#pragma unroll
            for (int j = 0; j < 7; ++j) {
                float s = 0.f;
#pragma unroll
                for (int k = 0; k < 7; ++k)
                    s += h1[k] * w[k * 7 + j] + f1p[k] * w[(7 + k) * 7 + j] + f2p[k] * w[(14 + k) * 7 + j];
                x2[j] = s;
                sx[j] += s; sq[j] += (double)s * (double)s;
            }
            x2[7] = 0.f;
            float4* q = reinterpret_cast<float4*>(x2o + (size_t)node * 8);
            q[0] = make_float4(x2[0], x2[1], x2[2], x2[3]);
            q[1] = make_float4(x2[4], x2[5], x2[6], x2[7]);
        }
    }
    double acc[14];
#pragma unroll
    for (int j = 0; j < 7; ++j) { acc[j] = sx[j]; acc[7 + j] = sq[j]; }
    blk_reduce_atomic<14>(acc, ds + 5);
}

// ---------- tiny: BN2 folded coefficients c0,c1 ----------
__global__ void k_t2(const double* __restrict__ ds, const float* __restrict__ g2,
                     const float* __restrict__ b2, float* __restrict__ fsg) {
    if (threadIdx.x || blockIdx.x) return;
    const double inv_n = 1.0 / (double)NNODES;
    for (int j = 0; j < 7; ++j) {
        float m = (float)(ds[5 + j] * inv_n);
        float v = (float)(ds[12 + j] * inv_n) - m * m;
        float ig = (1.f / sqrtf(v + BN_EPS)) * g2[j];
        fsg[21 + j] = b2[j] - m * ig;  // c0
        fsg[28 + j] = ig;              // c1
    }
}

// ---------- node: h2 column sums ----------
__global__ void __launch_bounds__(256) k_h2sum(const float* __restrict__ x2o, const float* __restrict__ fsg,
                                               double* __restrict__ ds, int n) {
    float c0[7], c1[7];
#pragma unroll
    for (int j = 0; j < 7; ++j) { c0[j] = fsg[21 + j]; c1[j] = fsg[28 + j]; }
    double acc[7] = {0, 0, 0, 0, 0, 0, 0};
    for (int i = blockIdx.x * blockDim.x + threadIdx.x; i < n; i += gridDim.x * blockDim.x) {
        const float4* p = reinterpret_cast<const float4*>(x2o + (size_t)i * 8);
        float4 a = p[0], b = p[1];
        float x[7] = {a.x, a.y, a.z, a.w, b.x, b.y, b.z};
#pragma unroll
        for (int j = 0; j < 7; ++j) acc[j] += (double)fmaxf(x[j] * c1[j] + c0[j], 0.f);
    }
    blk_reduce_atomic<7>(acc, ds + 19);
}

// ---------- tiny: embeddings + similarity MLP + sigmoid ----------
__global__ void k_final(const double* __restrict__ ds, const float* __restrict__ Wd, const float* __restrict__ bd,
                        const float* __restrict__ Ws0, const float* __restrict__ bs0,
                        const float* __restrict__ Ws1, const float* __restrict__ bs1,
                        const float* __restrict__ Ws2, const float* __restrict__ bs2,
                        const float* __restrict__ Ws3, const float* __restrict__ bs3,
                        const float* __restrict__ Wsim, const float* __restrict__ bsim,
                        float* __restrict__ out) {
    if (threadIdx.x || blockIdx.x) return;
    const double inv_n = 1.0 / (double)NNODES;
    float v[22];
    for (int g = 0; g < 2; ++g) {
        float hm[7];
        for (int j = 0; j < 7; ++j) hm[j] = (float)(ds[g * 26 + 19 + j] * inv_n);
        for (int r = 0; r < 11; ++r) {
            float s = bd[r];
            for (int j = 0; j < 7; ++j) s += hm[j] * Wd[j * 11 + r];
            v[g * 11 + r] = s;
        }
    }
    float h[7], h2[7];
    for (int j = 0; j < 7; ++j) {
        float s = bs0[j];
        for (int k = 0; k < 22; ++k) s += v[k] * Ws0[k * 7 + j];
        h[j] = s;
    }
    const float* Ws[3] = {Ws1, Ws2, Ws3};
    const float* bs[3] = {bs1, bs2, bs3};
    for (int l = 0; l < 3; ++l) {
        for (int j = 0; j < 7; ++j) {
            float s = bs[l][j];
            for (int k = 0; k < 7; ++k) s += h[k] * Ws[l][k * 7 + j];
            h2[j] = fmaxf(s, 0.f);
        }
        for (int j = 0; j < 7; ++j) h[j] = h2[j];
    }
    for (int r = 0; r < 12; ++r) {
        float s = bsim[r];
        for (int j = 0; j < 7; ++j) s += h[j] * Wsim[j * 12 + r];
        out[r] = 1.f / (1.f + expf(-s));
    }
}

extern "C" void kernel_launch(void* const* d_in, const int* in_sizes, int n_in,
                              void* d_out, int out_size, void* d_ws, size_t ws_size,
                              hipStream_t stream) {
    const int E = in_sizes[0];
    const int n = NNODES;
    const int* src1 = (const int*)d_in[0];
    const int* dst1 = (const int*)d_in[1];
    const int* src2 = (const int*)d_in[2];
    const int* dst2 = (const int*)d_in[3];
    const float* W_init = (const float*)d_in[5];
    const float* b_init = (const float*)d_in[6];
    const float* Wg  = (const float*)d_in[7];
    const float* bg  = (const float*)d_in[8];
    const float* Wt1 = (const float*)d_in[9];
    const float* g1  = (const float*)d_in[10];
    const float* b1  = (const float*)d_in[11];
    const float* Wt2 = (const float*)d_in[12];
    const float* g2  = (const float*)d_in[13];
    const float* b2  = (const float*)d_in[14];
    const float* Wd  = (const float*)d_in[15];
    const float* bd  = (const float*)d_in[16];
    const float* Ws0 = (const float*)d_in[17];
    const float* bs0 = (const float*)d_in[18];
    const float* Ws1 = (const float*)d_in[19];
    const float* bs1 = (const float*)d_in[20];
    const float* Ws2 = (const float*)d_in[21];
    const float* bs2 = (const float*)d_in[22];
    const float* Ws3 = (const float*)d_in[23];
    const float* bs3 = (const float*)d_in[24];
    const float* Wsim = (const float*)d_in[25];
    const float* bsim = (const float*)d_in[26];

    // workspace: 21n floats + (NBKT + NBKT+1 + NBKT) ints + E uints + scalars  (~74 MB)
    float* F     = (float*)d_ws;
    float* norm  = F;                        // n
    float* sdeg  = F + (size_t)n;            // n
    float* s1    = F + 2 * (size_t)n;        // n
    float* s1n   = F + 3 * (size_t)n;        // n
    float* s2    = F + 4 * (size_t)n;        // n
    float* h1n   = F + 5 * (size_t)n;        // 8n  (h1*norm; reused as x2o)
    float* f1n   = F + 13 * (size_t)n;       // 8n
    int*   gcnt  = (int*)(F + 21 * (size_t)n);        // NBKT
    int*   bb    = gcnt + NBKT;                        // NBKT+1
    int*   gcur  = bb + NBKT + 1;                      // NBKT
    unsigned int* pairs = (unsigned int*)(gcur + NBKT);// E
    float* fscal = (float*)(pairs + E);                // 128
    size_t dso = ((size_t)(fscal + 128 - F) + 1) & ~(size_t)1;
    double* dscal = (double*)(F + dso);                // 52 doubles

    const int EB  = (E + EPB - 1) / EPB;
    const int nbk = (n + 255) / 256;
    const int rbk = 1024;

    hipMemsetAsync(dscal, 0, 52 * sizeof(double), stream);
    k_t0<<<1, 1, 0, stream>>>(W_init, b_init, Wg, bg, Wt1, fscal);

    for (int g = 0; g < 2; ++g) {
        const int* src = g ? src2 : src1;
        const int* dst = g ? dst2 : dst1;
        float* fsg  = fscal + 28 + g * 35;
        double* dsg = dscal + g * 26;

        hipMemsetAsync(gcnt, 0, NBKT * sizeof(int), stream);
        k_bhist<<<EB, 256, 0, stream>>>(dst, gcnt, E);
        k_bscan<<<1, 1024, 0, stream>>>(gcnt, bb, gcur);
        k_bscat<<<EB, 256, 0, stream>>>(src, dst, gcur, pairs, E);

        k_deg<<<NBKT, 256, 0, stream>>>(pairs, bb, norm, sdeg, n);
        k_s1 <<<NBKT, 256, 0, stream>>>(pairs, bb, norm, s1, s1n, n);
        k_s2 <<<NBKT, 256, 0, stream>>>(pairs, bb, norm, s1, s1n, s2, dsg, n);
        k_t1<<<1, 1, 0, stream>>>(dsg, fscal, g1, b1, fsg);
        k_h1n<<<nbk, 256, 0, stream>>>(s1, s2, norm, fsg, h1n, n);
        k_f1 <<<NBKT, 256, 0, stream>>>(pairs, bb, norm, h1n, f1n, n);
        k_x2f<<<NBKT, 256, 0, stream>>>(pairs, bb, norm, sdeg, s1, s2, fsg, f1n, Wt2, h1n, dsg, n);
        k_t2<<<1, 1, 0, stream>>>(dsg, g2, b2, fsg);
        k_h2sum<<<rbk, 256, 0, stream>>>(h1n, fsg, dsg, n);
    }
    k_final<<<1, 1, 0, stream>>>(dscal, Wd, bd, Ws0, bs0, Ws1, bs1, Ws2, bs2, Ws3, bs3,
                                 Wsim, bsim, (float*)d_out);
}